// Round 2
// baseline (128.365 us; speedup 1.0000x reference)
//
#include <hip/hip_runtime.h>

// Signature kernel (dyadic order 1, sigma=1) for xs:(16,128,8), ys:(16,128,8) f32.
// One block per (bx,by) pair. Phase 1: RBF Gram + finite diff in LDS (f32, matching
// reference op order). Phase 2: Goursat PDE anti-diagonal wavefront in f64, one
// __syncthreads per diagonal. Output out[bx*16+by] = K_sig(xs[bx], ys[by]).

#define LX 128
#define D  8
#define MG 254          // refined grid M = N = (128-1)*2
#define NB 16           // batch

__global__ __launch_bounds__(256)
void sigkernel_kernel(const float* __restrict__ xs,
                      const float* __restrict__ ys,
                      float* __restrict__ out)
{
    __shared__ float sx[LX][D + 1];      // padded to 9 floats to dodge stride-8 banks
    __shared__ float sy[LX][D + 1];
    __shared__ float xsqv[LX];
    __shared__ float ysqv[LX];
    __shared__ float B[LX * LX];         // K (128x128), then quarter-diff (127x127)
    __shared__ double dg[3][256];        // rotating PDE diagonals

    const int t  = threadIdx.x;
    const int bx = blockIdx.x;
    const int by = blockIdx.y;
    const float* xp = xs + bx * (LX * D);
    const float* yp = ys + by * (LX * D);

    // ---- load x, y ----
    for (int e = t; e < LX * D; e += 256) {
        sx[e >> 3][e & 7] = xp[e];
        sy[e >> 3][e & 7] = yp[e];
    }
    __syncthreads();

    // ---- squared norms ----
    if (t < LX) {
        float sxx = 0.f, syy = 0.f;
        #pragma unroll
        for (int k = 0; k < D; ++k) {
            sxx += sx[t][k] * sx[t][k];
            syy += sy[t][k] * sy[t][k];
        }
        xsqv[t] = sxx;
        ysqv[t] = syy;
    }
    __syncthreads();

    // ---- K[i][j] = exp(-0.5*(|x_i|^2+|y_j|^2-2 x_i.y_j)) ----
    {
        const int j = t & 127;           // fixed column per thread
        float yr[D];
        #pragma unroll
        for (int k = 0; k < D; ++k) yr[k] = sy[j][k];
        const float ysq = ysqv[j];
        #pragma unroll
        for (int c = 0; c < 64; ++c) {
            const int e = t + c * 256;
            const int i = e >> 7;
            float dot = 0.f;
            #pragma unroll
            for (int k = 0; k < D; ++k) dot += sx[i][k] * yr[k];
            const float sq = xsqv[i] + ysq - 2.0f * dot;
            B[e] = expf(-0.5f * sq);
        }
    }
    __syncthreads();

    // ---- quarter-scaled second mixed difference, in place ----
    // A[p][q] (dyadic) = diff[p>>1][q>>1] / 4 ; store diff/4 at B[i*127+j]
    {
        float rv[64];
        #pragma unroll
        for (int c = 0; c < 64; ++c) {
            const int idx = t + c * 256;
            if (idx < 127 * 127) {
                const int i = idx / 127;
                const int j = idx - i * 127;
                rv[c] = 0.25f * (B[(i + 1) * 128 + (j + 1)] + B[i * 128 + j]
                               - B[(i + 1) * 128 + j]       - B[i * 128 + (j + 1)]);
            }
        }
        __syncthreads();
        #pragma unroll
        for (int c = 0; c < 64; ++c) {
            const int idx = t + c * 256;
            if (idx < 127 * 127) B[idx] = rv[c];
        }
    }

    // ---- PDE wavefront: grid (MG+1)x(MG+1), boundary 1, diagonals d=2..508 ----
    dg[0][t] = 1.0;   // diagonal d=0
    dg[1][t] = 1.0;   // diagonal d=1
    __syncthreads();

    double* p2 = &dg[0][0];
    double* p1 = &dg[1][0];
    double* cu = &dg[2][0];

    const int i = t;                      // row index along diagonal
    for (int d = 2; d <= 2 * MG; ++d) {
        double nv = 1.0;
        const int j = d - i;
        if (i >= 1 && i <= MG && j >= 1 && j <= MG) {
            const double inc  = (double)B[((i - 1) >> 1) * 127 + ((j - 1) >> 1)];
            const double k10  = p1[i - 1];
            const double k01  = p1[i];
            const double k00  = p2[i - 1];
            const double e12  = inc * inc * (1.0 / 12.0);
            nv = (k10 + k01) * (1.0 + 0.5 * inc + e12) - k00 * (1.0 - e12);
        }
        if (i <= MG) cu[i] = nv;
        __syncthreads();
        double* tmp = p2; p2 = p1; p1 = cu; cu = tmp;
    }

    if (t == 0) out[bx * NB + by] = (float)p1[MG];
}

extern "C" void kernel_launch(void* const* d_in, const int* in_sizes, int n_in,
                              void* d_out, int out_size, void* d_ws, size_t ws_size,
                              hipStream_t stream)
{
    const float* xs = (const float*)d_in[0];
    const float* ys = (const float*)d_in[1];
    float* out = (float*)d_out;
    dim3 grid(NB, NB);
    dim3 block(256);
    hipLaunchKernelGGL(sigkernel_kernel, grid, block, 0, stream, xs, ys, out);
}

// Round 3
// 89.479 us; speedup vs baseline: 1.4346x; 1.4346x over previous
//
#include <hip/hip_runtime.h>

// Signature kernel (dyadic order 1, sigma=1) for xs:(16,128,8), ys:(16,128,8) f32.
// One block (256 thr) per pair. Phase 1 (all 4 waves): RBF Gram K (128x128, f32) and
// quarter-scaled 2nd mixed difference in-place in LDS (stride 128, col 127 zeroed).
// Phase 2 (wave 0 only, ZERO barriers): Goursat PDE on the 255x255 refined grid as a
// register wavefront: lane l owns rows 4l+1..4l+4, all at column j = s - 2*l per step.
// Cross-lane handoff via one __shfl_up(f64) per step + 3-deep register FIFO (skew 2
// gives the shuffle 2 steps of slack). Out-of-range columns read a shared zero word
// (broadcast) -> inc=0 -> k11 = k10+k01-k00 keeps boundary 1s alive: no predication.
// PDE arithmetic in f64 (absmax margin 4x at round 2).

#define LX 128
#define D  8
#define NB 16
#define NBODY 190        // 190 double-steps = s = 1..380 ; result at s = 380

__global__ __launch_bounds__(256)
void sigkernel_kernel(const float* __restrict__ xs,
                      const float* __restrict__ ys,
                      float* __restrict__ out)
{
    __shared__ float sx[LX][D + 1];
    __shared__ float sy[LX][D + 1];
    __shared__ float xsqv[LX];
    __shared__ float ysqv[LX];
    __shared__ float B[LX * LX];   // K (stride 128), then 0.25*diff (stride 128, col 127 = 0)

    const int t  = threadIdx.x;
    const int bx = blockIdx.x;
    const int by = blockIdx.y;
    const float* xp = xs + bx * (LX * D);
    const float* yp = ys + by * (LX * D);

    // ---- load x, y ----
    for (int e = t; e < LX * D; e += 256) {
        sx[e >> 3][e & 7] = xp[e];
        sy[e >> 3][e & 7] = yp[e];
    }
    __syncthreads();

    // ---- squared norms ----
    if (t < LX) {
        float sxx = 0.f, syy = 0.f;
        #pragma unroll
        for (int k = 0; k < D; ++k) {
            sxx += sx[t][k] * sx[t][k];
            syy += sy[t][k] * sy[t][k];
        }
        xsqv[t] = sxx;
        ysqv[t] = syy;
    }
    __syncthreads();

    // ---- K[i][j] = exp(-0.5*(|x_i|^2+|y_j|^2-2 x_i.y_j)), stride 128 ----
    {
        const int j = t & 127;
        float yr[D];
        #pragma unroll
        for (int k = 0; k < D; ++k) yr[k] = sy[j][k];
        const float ysq = ysqv[j];
        #pragma unroll
        for (int c = 0; c < 64; ++c) {
            const int e = t + c * 256;
            const int i = e >> 7;
            float dot = 0.f;
            #pragma unroll
            for (int k = 0; k < D; ++k) dot += sx[i][k] * yr[k];
            const float sq = xsqv[i] + ysq - 2.0f * dot;
            B[e] = expf(-0.5f * sq);
        }
    }
    __syncthreads();

    // ---- quarter-scaled 2nd mixed diff, in place at stride 128 ----
    {
        float rv[64];
        #pragma unroll
        for (int c = 0; c < 64; ++c) {
            const int idx = t + c * 256;
            if (idx < 127 * 127) {
                const int i = idx / 127;
                const int j = idx - i * 127;
                rv[c] = 0.25f * (B[(i + 1) * 128 + (j + 1)] + B[i * 128 + j]
                               - B[(i + 1) * 128 + j]       - B[i * 128 + (j + 1)]);
            }
        }
        __syncthreads();
        #pragma unroll
        for (int c = 0; c < 64; ++c) {
            const int idx = t + c * 256;
            if (idx < 127 * 127) {
                const int i = idx / 127;
                const int j = idx - i * 127;
                B[i * 128 + j] = rv[c];
            }
        }
        if (t < 127) B[t * 128 + 127] = 0.f;   // zero pad col; word 127 is the clamp target
    }
    __syncthreads();

    // ---- waves 1..3 done; wave 0 runs the register wavefront (no more barriers) ----
    if (t >= 64) return;

    const int l = t;
    const int rowa = 2 * l;                              // dyadic row for rows 4l+1, 4l+2
    const int rowb = (2 * l + 1 > 126) ? 126 : 2 * l + 1; // rows 4l+3, 4l+4 (lane 63 dummy)
    const int baseA = rowa * 128;
    const int baseB = rowb * 128;
    const bool lane0 = (l == 0);

    double cur0 = 1.0, cur1 = 1.0, cur2 = 1.0, cur3 = 1.0;  // rows 4l+1..4l+4, col j-1
    double h0 = 1.0, h1 = 1.0, h2 = 1.0;                    // neighbor row-4l history

    // prefetch body 0: q(body k) = k - l
    float inA, inB;
    {
        const int q = -l;
        const bool cl = ((unsigned)q > 126u);
        inA = B[cl ? 127 : (baseA + q)];
        inB = B[cl ? 127 : (baseB + q)];
    }

    for (int k = 0; k < NBODY; ++k) {
        // coefficients for this body's dyadic cells (q = k - l), from prefetched inc
        const double ia = (double)inA;
        const double ib = (double)inB;
        const double ea = ia * ia * (1.0 / 12.0);
        const double eb = ib * ib * (1.0 / 12.0);
        const double c1a = 1.0 + 0.5 * ia + ea, c2a = 1.0 - ea;
        const double c1b = 1.0 + 0.5 * ib + eb, c2b = 1.0 - eb;

        // prefetch next body (slack ~1 body hides LDS latency)
        {
            const int qn = k + 1 - l;
            const bool cl = ((unsigned)qn > 126u);
            inA = B[cl ? 127 : (baseA + qn)];
            inB = B[cl ? 127 : (baseB + qn)];
        }

        #pragma unroll
        for (int sub = 0; sub < 2; ++sub) {
            // start of step s: h1 = K[4l][j], h2 = K[4l][j-1]
            const double k10 = lane0 ? 1.0 : h1;
            const double k00 = lane0 ? 1.0 : h2;
            const double n0 = (k10 + cur0) * c1a - k00  * c2a;
            const double n1 = (n0  + cur1) * c1a - cur0 * c2a;
            const double n2 = (n1  + cur2) * c1b - cur1 * c2b;
            const double n3 = (n2  + cur3) * c1b - cur2 * c2b;
            cur0 = n0; cur1 = n1; cur2 = n2; cur3 = n3;
            const double sh = __shfl_up(n3, 1);
            h2 = h1; h1 = h0; h0 = sh;
        }
    }

    // K[254][254]: row 254 = lane 63's second row, finished at s = 380
    if (l == 63) out[bx * NB + by] = (float)cur1;
}

extern "C" void kernel_launch(void* const* d_in, const int* in_sizes, int n_in,
                              void* d_out, int out_size, void* d_ws, size_t ws_size,
                              hipStream_t stream)
{
    const float* xs = (const float*)d_in[0];
    const float* ys = (const float*)d_in[1];
    float* out = (float*)d_out;
    dim3 grid(NB, NB);
    dim3 block(256);
    hipLaunchKernelGGL(sigkernel_kernel, grid, block, 0, stream, xs, ys, out);
}